// Round 10
// baseline (302.338 us; speedup 1.0000x reference)
//
#include <hip/hip_runtime.h>
#include <math.h>

#define B   128
#define V   128000
#define PL  2048
#define OL  256
#define BPR 25          // blocks per row in heavy passes (25*5*1024 = 128000)
#define ITERS 5
#define SLICE (ITERS * 1024)   // 5120 elements per block
#define SW  160                // slice bitmask words (5120/32)
#define TLOC 128        // per-block emission floor (> max top_k=99; superset proof)
#define GMAX 240        // per-block emission cap for guess path (25*240 <= CAP)
#define CAP  6144       // per-row candidate capacity
#define FP16_TINY 6.103515625e-05f
#define QZ   1.80f      // z-score: expected count 5120*P(z>1.80)=184 in [128,240]

// padded histogram index (fallback path): stride-17 kills chunk-sum conflicts
#define HBINS 4096
#define HIDX(b) ((b) + ((b) >> 4))
#define HSZ (HBINS + (HBINS >> 4))   // 4352 words

// monotone float->uint key (ascending)
__device__ __forceinline__ unsigned key_of(float f) {
    unsigned u = __float_as_uint(f);
    unsigned m = (unsigned)(((int)u) >> 31) | 0x80000000u;
    return u ^ m;
}
__device__ __forceinline__ float key_inv(unsigned k) {
    unsigned u = (k & 0x80000000u) ? (k ^ 0x80000000u) : ~k;
    return __uint_as_float(u);
}

// Deterministic transform; contract(off) so every call site lowers identically.
__device__ __forceinline__ float xform(float x, int pm, int om,
                                       float rp, float rrp, float pres, float itt) {
#pragma clang fp contract(off)
    float m = (pm | om) ? ((x > 0.0f) ? rrp : rp) : 1.0f;
    float l = x * m;
    if (om) l = l - pres;
    return l * itt;
}

// ---- wave-level scan/reduce helpers (wave64) ----
__device__ __forceinline__ unsigned wave_suffix_u(unsigned x, int lane) {
#pragma unroll
    for (int o = 1; o < 64; o <<= 1) {
        unsigned a = __shfl_down(x, o);
        if (lane + o < 64) x += a;
    }
    return x;
}
__device__ __forceinline__ unsigned wave_prefix_u(unsigned x, int lane) {
#pragma unroll
    for (int o = 1; o < 64; o <<= 1) {
        unsigned a = __shfl_up(x, o);
        if (lane >= o) x += a;
    }
    return x;
}
__device__ __forceinline__ double wave_suffix_d(double x, int lane) {
#pragma unroll
    for (int o = 1; o < 64; o <<= 1) {
        double a = __shfl_down(x, o);
        if (lane + o < 64) x += a;
    }
    return x;
}
__device__ __forceinline__ double wave_sum_d(double x) {
#pragma unroll
    for (int o = 1; o < 64; o <<= 1) x += __shfl_xor(x, o);
    return x;
}
__device__ __forceinline__ unsigned wave_sum_u(unsigned x) {
#pragma unroll
    for (int o = 1; o < 64; o <<= 1) x += __shfl_xor(x, o);
    return x;
}

// Heavy pass, READ-ONLY streams: LDS token-mask rebuild, transform -> keys,
// candidate emission (guess-threshold + exact fallback). NO pm/om writes —
// those moved to the write-segregated k_final.
__global__ __launch_bounds__(256) void k_main(
    const float* __restrict__ logits,
    const int* __restrict__ ptok, const int* __restrict__ otok,
    const float* __restrict__ rep, const float* __restrict__ pres,
    const float* __restrict__ temp,
    unsigned* __restrict__ cnt, unsigned long long* __restrict__ cand)
{
    __shared__ unsigned mp[SW];
    __shared__ unsigned mo[SW];
    __shared__ unsigned h[HSZ];       // touched only on fallback
    __shared__ unsigned wsum[4];
    __shared__ int s_beta;
    __shared__ unsigned s_base, s_total;
    int r = blockIdx.y;
    int c0 = blockIdx.x * SLICE;
    int t = threadIdx.x;
    int lane = t & 63, wid = t >> 6;
    if (t < SW) { mp[t] = 0u; mo[t] = 0u; }
    __syncthreads();
    const int* prow = ptok + (size_t)r * PL;
    const int* orow = otok + (size_t)r * OL;
    for (int i = t; i < PL; i += 256) {
        unsigned lt = (unsigned)(prow[i] - c0);
        if (lt < (unsigned)SLICE) atomicOr(&mp[lt >> 5], 1u << (lt & 31));
    }
    for (int i = t; i < OL; i += 256) {
        unsigned lt = (unsigned)(orow[i] - c0);
        if (lt < (unsigned)SLICE) atomicOr(&mo[lt >> 5], 1u << (lt & 31));
    }
    __syncthreads();
    float rp = rep[r], pp = pres[r];
    float tt = temp[r]; tt = (tt < 1e-5f) ? 1.0f : tt;
    float rrp = 1.0f / rp;
    float itt = 1.0f / tt;
    const float* lrow = logits + (size_t)r * V;
    uint4 kv4[ITERS];
#pragma unroll
    for (int it = 0; it < ITERS; it++) {
        int li = it * 1024 + t * 4;       // local slice index
        int i = c0 + li;                  // global index
        float4 x = *(const float4*)(lrow + i);
        unsigned wp = mp[li >> 5], wo = mo[li >> 5];
        int sh = li & 31;
        float xs[4] = {x.x, x.y, x.z, x.w};
        unsigned ks[4];
#pragma unroll
        for (int j = 0; j < 4; j++) {
            int p = (wp >> (sh + j)) & 1;
            int o = (wo >> (sh + j)) & 1;
            float l = xform(xs[j], p, o, rp, rrp, pp, itt);
            ks[j] = key_of(l);
        }
        kv4[it] = make_uint4(ks[0], ks[1], ks[2], ks[3]);
    }
    // ---- guessed threshold + exact count verification ----
    unsigned gk = key_of(QZ * 4.0f * itt);
    unsigned myc = 0;
#pragma unroll
    for (int it = 0; it < ITERS; it++) {
        unsigned ks[4] = {kv4[it].x, kv4[it].y, kv4[it].z, kv4[it].w};
#pragma unroll
        for (int j = 0; j < 4; j++)
            if (ks[j] >= gk) myc++;
    }
    unsigned pfx = wave_prefix_u(myc, lane);
    if (lane == 63) wsum[wid] = pfx;
    __syncthreads();
    unsigned pv = pfx;
#pragma unroll
    for (int w2 = 0; w2 < 4; w2++) if (w2 < wid) pv += wsum[w2];
    if (t == 255) s_total = pv;
    __syncthreads();
    unsigned total = s_total;
    unsigned betaKey;
    if (total >= TLOC && total <= GMAX) {
        betaKey = gk;            // common path: no histogram, no LDS atomics
    } else {
        // ---- exact histogram fallback (rare) ----
        for (int i = t; i < HSZ; i += 256) h[i] = 0u;
        __syncthreads();
#pragma unroll
        for (int it = 0; it < ITERS; it++) {
            unsigned ks[4] = {kv4[it].x, kv4[it].y, kv4[it].z, kv4[it].w};
#pragma unroll
            for (int j = 0; j < 4; j++)
                atomicAdd(&h[HIDX(ks[j] >> 20)], 1u);
        }
        __syncthreads();
        unsigned cs = 0;
#pragma unroll
        for (int j = 0; j < 16; j++) cs += h[HIDX(t * 16 + j)];
        unsigned sfx = wave_suffix_u(cs, lane);
        if (lane == 0) wsum[wid] = sfx;
        __syncthreads();
        unsigned suf = sfx;
#pragma unroll
        for (int w2 = 0; w2 < 4; w2++) if (w2 > wid) suf += wsum[w2];
        unsigned Snext = suf - cs;
        if (suf >= TLOC && Snext < TLOC) {
            unsigned run = Snext;
            int beta = t * 16;
            for (int j = 15; j >= 0; j--) {
                run += h[HIDX(t * 16 + j)];
                if (run >= TLOC) { beta = t * 16 + j; break; }
            }
            s_beta = beta;
        }
        __syncthreads();
        betaKey = ((unsigned)s_beta) << 20;
        myc = 0;
#pragma unroll
        for (int it = 0; it < ITERS; it++) {
            unsigned ks[4] = {kv4[it].x, kv4[it].y, kv4[it].z, kv4[it].w};
#pragma unroll
            for (int j = 0; j < 4; j++)
                if (ks[j] >= betaKey) myc++;
        }
        __syncthreads();            // wsum reuse guard
        pfx = wave_prefix_u(myc, lane);
        if (lane == 63) wsum[wid] = pfx;
        __syncthreads();
        pv = pfx;
#pragma unroll
        for (int w2 = 0; w2 < 4; w2++) if (w2 < wid) pv += wsum[w2];
    }
    if (t == 255) s_base = atomicAdd(&cnt[r], pv);   // pv@255 == block total
    __syncthreads();
    unsigned w = s_base + (pv - myc);                // base + exclusive prefix
#pragma unroll
    for (int it = 0; it < ITERS; it++) {
        unsigned ks[4] = {kv4[it].x, kv4[it].y, kv4[it].z, kv4[it].w};
#pragma unroll
        for (int j = 0; j < 4; j++) {
            unsigned key = ks[j];
            if (key >= betaKey) {
                if (w < (unsigned)CAP) {
                    int idx = c0 + it * 1024 + t * 4 + j;
                    cand[(size_t)r * CAP + w] =
                        ((unsigned long long)key << 32) | (unsigned)idx;
                }
                w++;
            }
        }
    }
}

// Per-row: candidates -> LDS, radix-select k-th key, gather kept (<=256),
// rank-based sort, f64 positional top-p tail, emit explicit keep-list.
// (R7-proven kernel, verbatim.)
__global__ __launch_bounds__(256) void k_select(
    const unsigned* __restrict__ cnt, const unsigned long long* __restrict__ cand,
    const int* __restrict__ topk, const float* __restrict__ topp,
    float4* __restrict__ params, unsigned* __restrict__ kn,
    int* __restrict__ kidx, float* __restrict__ kprob)
{
    __shared__ unsigned long long list[CAP];
    __shared__ unsigned long long kv[256];
    __shared__ unsigned rh[256];
    __shared__ double wD[4];
    __shared__ unsigned wU[4];
    __shared__ unsigned s_prefix, s_krem, s_kcnt;
    int r = blockIdx.x;
    int t = threadIdx.x;
    int lane = t & 63, wid = t >> 6;
    int n = (int)min(cnt[r], (unsigned)CAP);
    const unsigned long long* crow = cand + (size_t)r * CAP;
    for (int i = t; i < n; i += 256) list[i] = crow[i];
    int k = topk[r]; k = max(1, min(k, 127));
    if (t == 0) { s_prefix = 0u; s_krem = (unsigned)k; }
    __syncthreads();
    for (int round = 3; round >= 0; round--) {
        int shift = round * 8;
        unsigned prefix = s_prefix;
        unsigned krem = s_krem;
        unsigned maskAbove = (round == 3) ? 0u : (0xFFFFFFFFu << (shift + 8));
        rh[t] = 0u;
        __syncthreads();
        for (int i = t; i < n; i += 256) {
            unsigned key = (unsigned)(list[i] >> 32);
            if ((key & maskAbove) == (prefix & maskAbove))
                atomicAdd(&rh[(key >> shift) & 255u], 1u);
        }
        __syncthreads();
        unsigned vv = rh[t];
        unsigned sfx = wave_suffix_u(vv, lane);
        if (lane == 0) wU[wid] = sfx;
        __syncthreads();
        unsigned suf = sfx;
#pragma unroll
        for (int w2 = 0; w2 < 4; w2++) if (w2 > wid) suf += wU[w2];
        unsigned Sx = suf - vv;
        if (suf >= krem && Sx < krem) {
            s_prefix = prefix | ((unsigned)t << shift);
            s_krem = krem - Sx;
        }
        __syncthreads();
    }
    unsigned thrkey = s_prefix;   // k-th largest value key; ties all kept
    if (t == 0) s_kcnt = 0u;
    __syncthreads();
    for (int i = t; i < n; i += 256) {
        if ((unsigned)(list[i] >> 32) >= thrkey) {
            unsigned pos = atomicAdd(&s_kcnt, 1u);
            if (pos < 256u) kv[pos] = list[i];
        }
    }
    __syncthreads();
    int K = (int)min(s_kcnt, 256u);
    if (t >= K) kv[t] = 0ULL;
    __syncthreads();
    // rank-based sort: distinct u64s -> unique ranks; zeros stay in [K,256)
    unsigned long long my = kv[t];
    int rank = 0;
#pragma unroll 8
    for (int i = 0; i < 256; i++) rank += (kv[i] > my) ? 1 : 0;
    __syncthreads();
    if (t < K) kv[rank] = my;
    __syncthreads();
    // ---- parallel positional top-p tail (f64; perturbation ~1e-15 << margins) ----
    float Mxf = key_inv((unsigned)(kv[0] >> 32));
    double MxD = (double)Mxf;
    double e_t = (t < K) ? exp((double)key_inv((unsigned)(kv[t] >> 32)) - MxD)
                         : 0.0;
    double red = wave_sum_d(e_t);
    if (lane == 0) wD[wid] = red;
    __syncthreads();
    double S = wD[0] + wD[1] + wD[2] + wD[3];
    __syncthreads();
    double sv = wave_suffix_d(e_t, lane);
    if (lane == 0) wD[wid] = sv;
    __syncthreads();
    double suf_t = sv;
#pragma unroll
    for (int w2 = 0; w2 < 4; w2++) if (w2 > wid) suf_t += wD[w2];
    double e_tinyD = exp((double)FP16_TINY - MxD);
    double Z1 = (double)(V - K) * e_tinyD + S;
    double base = (double)(V - K) * e_tinyD / Z1;
    double thresh = 1.0 - (double)topp[r];
    unsigned flag = (t >= 1 && t < K && (base + suf_t / Z1) <= thresh) ? 1u : 0u;
    unsigned fr = wave_sum_u(flag);
    if (lane == 0) wU[wid] = fr;
    __syncthreads();
    int cm = (int)(wU[0] + wU[1] + wU[2] + wU[3]);
    int ns = K - cm;              // >= 1 (reference forces top element kept)
    __syncthreads();
    double e2 = (t < ns) ? e_t : 0.0;
    double r2 = wave_sum_d(e2);
    if (lane == 0) wD[wid] = r2;
    __syncthreads();
    double S2 = wD[0] + wD[1] + wD[2] + wD[3];
    float tiny_e = expf(FP16_TINY - Mxf);
    double Z2 = (double)(V - ns) * (double)tiny_e + S2;
    float invZ2 = (float)(1.0 / Z2);
    if (t == 0) {
        params[r] = make_float4(key_inv((unsigned)(kv[ns - 1] >> 32)), Mxf,
                                invZ2, tiny_e * invZ2);
        kn[r] = (unsigned)ns;
    }
    // keep-list: kept set == kv[0..ns)
    if (t < ns) {
        unsigned long long e = kv[t];
        unsigned key = (unsigned)(e >> 32);
        kidx[(size_t)r * 256 + t] = (int)(e & 0xFFFFFFFFu);
        kprob[(size_t)r * 256 + t] = expf(key_inv(key) - Mxf) * invZ2;
    }
}

// Final pass, WRITE-ONLY streams: LDS token-mask rebuild (cheap, L2-hot),
// writes pm + om + ptiny-filled probs (196.6 MB pure write), then <=256
// scattered keep overwrites per row.
__global__ __launch_bounds__(256) void k_final(
    const int* __restrict__ ptok, const int* __restrict__ otok,
    const float4* __restrict__ params, const unsigned* __restrict__ kn,
    const int* __restrict__ kidx, const float* __restrict__ kprob,
    float* __restrict__ outPm, float* __restrict__ outOm,
    float* __restrict__ probs)
{
    __shared__ unsigned mp[SW];
    __shared__ unsigned mo[SW];
    int r = blockIdx.y;
    int c0 = blockIdx.x * SLICE;
    int t = threadIdx.x;
    if (t < SW) { mp[t] = 0u; mo[t] = 0u; }
    __syncthreads();
    const int* prow = ptok + (size_t)r * PL;
    const int* orow = otok + (size_t)r * OL;
    for (int i = t; i < PL; i += 256) {
        unsigned lt = (unsigned)(prow[i] - c0);
        if (lt < (unsigned)SLICE) atomicOr(&mp[lt >> 5], 1u << (lt & 31));
    }
    for (int i = t; i < OL; i += 256) {
        unsigned lt = (unsigned)(orow[i] - c0);
        if (lt < (unsigned)SLICE) atomicOr(&mo[lt >> 5], 1u << (lt & 31));
    }
    __syncthreads();
    float ptiny = params[r].w;
    float* prrow = probs + (size_t)r * V;
    float* pmrow = outPm + (size_t)r * V;
    float* omrow = outOm + (size_t)r * V;
    float4 pv4 = make_float4(ptiny, ptiny, ptiny, ptiny);
#pragma unroll
    for (int it = 0; it < ITERS; it++) {
        int li = it * 1024 + t * 4;
        int i = c0 + li;
        unsigned wp = mp[li >> 5], wo = mo[li >> 5];
        int sh = li & 31;
        float fp[4], fo[4];
#pragma unroll
        for (int j = 0; j < 4; j++) {
            fp[j] = (float)((wp >> (sh + j)) & 1);
            fo[j] = (float)((wo >> (sh + j)) & 1);
        }
        *(float4*)(pmrow + i) = make_float4(fp[0], fp[1], fp[2], fp[3]);
        *(float4*)(omrow + i) = make_float4(fo[0], fo[1], fo[2], fo[3]);
        *(float4*)(prrow + i) = pv4;
    }
    __syncthreads();
    int ns = (int)kn[r];
    int hi = c0 + SLICE;
    for (int i = t; i < ns; i += 256) {
        int idx = kidx[(size_t)r * 256 + i];
        if (idx >= c0 && idx < hi) prrow[idx] = kprob[(size_t)r * 256 + i];
    }
}

extern "C" void kernel_launch(void* const* d_in, const int* in_sizes, int n_in,
                              void* d_out, int out_size, void* d_ws, size_t ws_size,
                              hipStream_t stream) {
    const float* logits = (const float*)d_in[0];
    const int* ptok     = (const int*)d_in[1];
    const int* otok     = (const int*)d_in[2];
    const float* pres   = (const float*)d_in[3];
    // d_in[4] = frequency_penalties: computed but never applied in reference
    const float* rep    = (const float*)d_in[5];
    const float* temp   = (const float*)d_in[6];
    const int* topk     = (const int*)d_in[7];
    const float* topp   = (const float*)d_in[8];

    float* out_probs = (float*)d_out;
    float* out_pm = out_probs + (size_t)B * V;
    float* out_om = out_pm + (size_t)B * V;

    unsigned* ws0 = (unsigned*)d_ws;
    float4* params = (float4*)d_ws;              // 128 * 16B at ws base
    unsigned* cnt  = ws0 + 512;                  // 128 u32
    unsigned* kn   = ws0 + 640;                  // 128 u32
    unsigned long long* cand =
        (unsigned long long*)(ws0 + 768);        // 8B-aligned; 128*CAP u64
    int* kidx      = (int*)(cand + (size_t)B * CAP);   // 128*256 i32
    float* kprob   = (float*)(kidx + B * 256);         // 128*256 f32

    // zero per-row candidate counters (tiny; graph-capture-safe)
    hipMemsetAsync(cnt, 0, B * sizeof(unsigned), stream);

    dim3 g(BPR, B);
    k_main<<<g, 256, 0, stream>>>(logits, ptok, otok, rep, pres, temp,
                                  cnt, cand);
    k_select<<<B, 256, 0, stream>>>(cnt, cand, topk, topp,
                                    params, kn, kidx, kprob);
    k_final<<<g, 256, 0, stream>>>(ptok, otok, params, kn, kidx, kprob,
                                   out_pm, out_om, out_probs);
}

// Round 11
// 293.930 us; speedup vs baseline: 1.0286x; 1.0286x over previous
//
#include <hip/hip_runtime.h>
#include <math.h>

#define B   128
#define V   128000
#define PL  2048
#define OL  256
#define BPR 25          // blocks per row in heavy passes (25*5*1024 = 128000)
#define ITERS 5
#define SLICE (ITERS * 1024)   // 5120 elements per block
#define SW  160                // slice bitmask words (5120/32)
#define TLOC 128        // per-block emission floor (> max top_k=99; superset proof)
#define GMAX 240        // per-block emission cap for guess path (25*240 <= CAP)
#define CAP  6144       // per-row candidate capacity
#define FP16_TINY 6.103515625e-05f
#define QZ   1.80f      // z-score: expected count 5120*P(z>1.80)=184 in [128,240]

// padded histogram index (fallback path): stride-17 kills chunk-sum conflicts
#define HBINS 4096
#define HIDX(b) ((b) + ((b) >> 4))
#define HSZ (HBINS + (HBINS >> 4))   // 4352 words

// monotone float->uint key (ascending)
__device__ __forceinline__ unsigned key_of(float f) {
    unsigned u = __float_as_uint(f);
    unsigned m = (unsigned)(((int)u) >> 31) | 0x80000000u;
    return u ^ m;
}
__device__ __forceinline__ float key_inv(unsigned k) {
    unsigned u = (k & 0x80000000u) ? (k ^ 0x80000000u) : ~k;
    return __uint_as_float(u);
}

// Deterministic transform; contract(off) so every call site lowers identically.
__device__ __forceinline__ float xform(float x, int pm, int om,
                                       float rp, float rrp, float pres, float itt) {
#pragma clang fp contract(off)
    float m = (pm | om) ? ((x > 0.0f) ? rrp : rp) : 1.0f;
    float l = x * m;
    if (om) l = l - pres;
    return l * itt;
}

// ---- wave-level scan/reduce helpers (wave64) ----
__device__ __forceinline__ unsigned wave_suffix_u(unsigned x, int lane) {
#pragma unroll
    for (int o = 1; o < 64; o <<= 1) {
        unsigned a = __shfl_down(x, o);
        if (lane + o < 64) x += a;
    }
    return x;
}
__device__ __forceinline__ unsigned wave_prefix_u(unsigned x, int lane) {
#pragma unroll
    for (int o = 1; o < 64; o <<= 1) {
        unsigned a = __shfl_up(x, o);
        if (lane >= o) x += a;
    }
    return x;
}
__device__ __forceinline__ double wave_suffix_d(double x, int lane) {
#pragma unroll
    for (int o = 1; o < 64; o <<= 1) {
        double a = __shfl_down(x, o);
        if (lane + o < 64) x += a;
    }
    return x;
}
__device__ __forceinline__ double wave_sum_d(double x) {
#pragma unroll
    for (int o = 1; o < 64; o <<= 1) x += __shfl_xor(x, o);
    return x;
}
__device__ __forceinline__ unsigned wave_sum_u(unsigned x) {
#pragma unroll
    for (int o = 1; o < 64; o <<= 1) x += __shfl_xor(x, o);
    return x;
}

// Heavy pass: builds the block's 5120-token slice bitmask IN LDS from the
// raw token lists (no global bitmask round-trip, no k_scatter launch),
// writes pm/om outputs, emits candidates (guess-threshold + exact fallback).
__global__ __launch_bounds__(256) void k_main(
    const float* __restrict__ logits,
    const int* __restrict__ ptok, const int* __restrict__ otok,
    const float* __restrict__ rep, const float* __restrict__ pres,
    const float* __restrict__ temp,
    float* __restrict__ outPm, float* __restrict__ outOm,
    unsigned* __restrict__ cnt, unsigned long long* __restrict__ cand)
{
    __shared__ unsigned mp[SW];
    __shared__ unsigned mo[SW];
    __shared__ unsigned h[HSZ];       // touched only on fallback
    __shared__ unsigned wsum[4];
    __shared__ int s_beta;
    __shared__ unsigned s_base, s_total;
    int r = blockIdx.y;
    int c0 = blockIdx.x * SLICE;
    int t = threadIdx.x;
    int lane = t & 63, wid = t >> 6;
    // zero slice masks
    if (t < SW) { mp[t] = 0u; mo[t] = 0u; }
    __syncthreads();
    // scatter in-range tokens into LDS bitmask (unsigned trick: lt<SLICE
    // rejects both below-range and above-range)
    const int* prow = ptok + (size_t)r * PL;
    const int* orow = otok + (size_t)r * OL;
    for (int i = t; i < PL; i += 256) {
        unsigned lt = (unsigned)(prow[i] - c0);
        if (lt < (unsigned)SLICE) atomicOr(&mp[lt >> 5], 1u << (lt & 31));
    }
    for (int i = t; i < OL; i += 256) {
        unsigned lt = (unsigned)(orow[i] - c0);
        if (lt < (unsigned)SLICE) atomicOr(&mo[lt >> 5], 1u << (lt & 31));
    }
    __syncthreads();
    float rp = rep[r], pp = pres[r];
    float tt = temp[r]; tt = (tt < 1e-5f) ? 1.0f : tt;
    float rrp = 1.0f / rp;
    float itt = 1.0f / tt;
    const float* lrow = logits + (size_t)r * V;
    float* pmrow = outPm + (size_t)r * V;
    float* omrow = outOm + (size_t)r * V;
    uint4 kv4[ITERS];
#pragma unroll
    for (int it = 0; it < ITERS; it++) {
        int li = it * 1024 + t * 4;       // local slice index
        int i = c0 + li;                  // global index
        float4 x = *(const float4*)(lrow + i);
        unsigned wp = mp[li >> 5], wo = mo[li >> 5];
        int sh = li & 31;
        float xs[4] = {x.x, x.y, x.z, x.w};
        unsigned ks[4];
        float fp[4], fo[4];
#pragma unroll
        for (int j = 0; j < 4; j++) {
            int p = (wp >> (sh + j)) & 1;
            int o = (wo >> (sh + j)) & 1;
            float l = xform(xs[j], p, o, rp, rrp, pp, itt);
            ks[j] = key_of(l);
            fp[j] = (float)p; fo[j] = (float)o;
        }
        kv4[it] = make_uint4(ks[0], ks[1], ks[2], ks[3]);
        *(float4*)(pmrow + i) = make_float4(fp[0], fp[1], fp[2], fp[3]);
        *(float4*)(omrow + i) = make_float4(fo[0], fo[1], fo[2], fo[3]);
    }
    // ---- guessed threshold + exact count verification ----
    unsigned gk = key_of(QZ * 4.0f * itt);
    unsigned myc = 0;
#pragma unroll
    for (int it = 0; it < ITERS; it++) {
        unsigned ks[4] = {kv4[it].x, kv4[it].y, kv4[it].z, kv4[it].w};
#pragma unroll
        for (int j = 0; j < 4; j++)
            if (ks[j] >= gk) myc++;
    }
    unsigned pfx = wave_prefix_u(myc, lane);
    if (lane == 63) wsum[wid] = pfx;
    __syncthreads();
    unsigned pv = pfx;
#pragma unroll
    for (int w2 = 0; w2 < 4; w2++) if (w2 < wid) pv += wsum[w2];
    if (t == 255) s_total = pv;
    __syncthreads();
    unsigned total = s_total;
    unsigned betaKey;
    if (total >= TLOC && total <= GMAX) {
        betaKey = gk;            // common path: no histogram, no LDS atomics
    } else {
        // ---- exact histogram fallback (rare) ----
        for (int i = t; i < HSZ; i += 256) h[i] = 0u;
        __syncthreads();
#pragma unroll
        for (int it = 0; it < ITERS; it++) {
            unsigned ks[4] = {kv4[it].x, kv4[it].y, kv4[it].z, kv4[it].w};
#pragma unroll
            for (int j = 0; j < 4; j++)
                atomicAdd(&h[HIDX(ks[j] >> 20)], 1u);
        }
        __syncthreads();
        unsigned cs = 0;
#pragma unroll
        for (int j = 0; j < 16; j++) cs += h[HIDX(t * 16 + j)];
        unsigned sfx = wave_suffix_u(cs, lane);
        if (lane == 0) wsum[wid] = sfx;
        __syncthreads();
        unsigned suf = sfx;
#pragma unroll
        for (int w2 = 0; w2 < 4; w2++) if (w2 > wid) suf += wsum[w2];
        unsigned Snext = suf - cs;
        if (suf >= TLOC && Snext < TLOC) {
            unsigned run = Snext;
            int beta = t * 16;
            for (int j = 15; j >= 0; j--) {
                run += h[HIDX(t * 16 + j)];
                if (run >= TLOC) { beta = t * 16 + j; break; }
            }
            s_beta = beta;
        }
        __syncthreads();
        betaKey = ((unsigned)s_beta) << 20;
        myc = 0;
#pragma unroll
        for (int it = 0; it < ITERS; it++) {
            unsigned ks[4] = {kv4[it].x, kv4[it].y, kv4[it].z, kv4[it].w};
#pragma unroll
            for (int j = 0; j < 4; j++)
                if (ks[j] >= betaKey) myc++;
        }
        __syncthreads();            // wsum reuse guard
        pfx = wave_prefix_u(myc, lane);
        if (lane == 63) wsum[wid] = pfx;
        __syncthreads();
        pv = pfx;
#pragma unroll
        for (int w2 = 0; w2 < 4; w2++) if (w2 < wid) pv += wsum[w2];
    }
    if (t == 255) s_base = atomicAdd(&cnt[r], pv);   // pv@255 == block total
    __syncthreads();
    unsigned w = s_base + (pv - myc);                // base + exclusive prefix
#pragma unroll
    for (int it = 0; it < ITERS; it++) {
        unsigned ks[4] = {kv4[it].x, kv4[it].y, kv4[it].z, kv4[it].w};
#pragma unroll
        for (int j = 0; j < 4; j++) {
            unsigned key = ks[j];
            if (key >= betaKey) {
                if (w < (unsigned)CAP) {
                    int idx = c0 + it * 1024 + t * 4 + j;
                    cand[(size_t)r * CAP + w] =
                        ((unsigned long long)key << 32) | (unsigned)idx;
                }
                w++;
            }
        }
    }
}

// Per-row: candidates -> LDS, radix-select k-th key, gather kept (<=256),
// rank-based sort, f64 positional top-p tail, emit explicit keep-list.
__global__ __launch_bounds__(256) void k_select(
    const unsigned* __restrict__ cnt, const unsigned long long* __restrict__ cand,
    const int* __restrict__ topk, const float* __restrict__ topp,
    float4* __restrict__ params, unsigned* __restrict__ kn,
    int* __restrict__ kidx, float* __restrict__ kprob)
{
    __shared__ unsigned long long list[CAP];
    __shared__ unsigned long long kv[256];
    __shared__ unsigned rh[256];
    __shared__ double wD[4];
    __shared__ unsigned wU[4];
    __shared__ unsigned s_prefix, s_krem, s_kcnt;
    int r = blockIdx.x;
    int t = threadIdx.x;
    int lane = t & 63, wid = t >> 6;
    int n = (int)min(cnt[r], (unsigned)CAP);
    const unsigned long long* crow = cand + (size_t)r * CAP;
    for (int i = t; i < n; i += 256) list[i] = crow[i];
    int k = topk[r]; k = max(1, min(k, 127));
    if (t == 0) { s_prefix = 0u; s_krem = (unsigned)k; }
    __syncthreads();
    for (int round = 3; round >= 0; round--) {
        int shift = round * 8;
        unsigned prefix = s_prefix;
        unsigned krem = s_krem;
        unsigned maskAbove = (round == 3) ? 0u : (0xFFFFFFFFu << (shift + 8));
        rh[t] = 0u;
        __syncthreads();
        for (int i = t; i < n; i += 256) {
            unsigned key = (unsigned)(list[i] >> 32);
            if ((key & maskAbove) == (prefix & maskAbove))
                atomicAdd(&rh[(key >> shift) & 255u], 1u);
        }
        __syncthreads();
        unsigned vv = rh[t];
        unsigned sfx = wave_suffix_u(vv, lane);
        if (lane == 0) wU[wid] = sfx;
        __syncthreads();
        unsigned suf = sfx;
#pragma unroll
        for (int w2 = 0; w2 < 4; w2++) if (w2 > wid) suf += wU[w2];
        unsigned Sx = suf - vv;
        if (suf >= krem && Sx < krem) {
            s_prefix = prefix | ((unsigned)t << shift);
            s_krem = krem - Sx;
        }
        __syncthreads();
    }
    unsigned thrkey = s_prefix;   // k-th largest value key; ties all kept
    if (t == 0) s_kcnt = 0u;
    __syncthreads();
    for (int i = t; i < n; i += 256) {
        if ((unsigned)(list[i] >> 32) >= thrkey) {
            unsigned pos = atomicAdd(&s_kcnt, 1u);
            if (pos < 256u) kv[pos] = list[i];
        }
    }
    __syncthreads();
    int K = (int)min(s_kcnt, 256u);
    if (t >= K) kv[t] = 0ULL;
    __syncthreads();
    // rank-based sort: distinct u64s -> unique ranks; zeros stay in [K,256)
    unsigned long long my = kv[t];
    int rank = 0;
#pragma unroll 8
    for (int i = 0; i < 256; i++) rank += (kv[i] > my) ? 1 : 0;
    __syncthreads();
    if (t < K) kv[rank] = my;
    __syncthreads();
    // ---- parallel positional top-p tail (f64; perturbation ~1e-15 << margins) ----
    float Mxf = key_inv((unsigned)(kv[0] >> 32));
    double MxD = (double)Mxf;
    double e_t = (t < K) ? exp((double)key_inv((unsigned)(kv[t] >> 32)) - MxD)
                         : 0.0;
    double red = wave_sum_d(e_t);
    if (lane == 0) wD[wid] = red;
    __syncthreads();
    double S = wD[0] + wD[1] + wD[2] + wD[3];
    __syncthreads();
    double sv = wave_suffix_d(e_t, lane);
    if (lane == 0) wD[wid] = sv;
    __syncthreads();
    double suf_t = sv;
#pragma unroll
    for (int w2 = 0; w2 < 4; w2++) if (w2 > wid) suf_t += wD[w2];
    double e_tinyD = exp((double)FP16_TINY - MxD);
    double Z1 = (double)(V - K) * e_tinyD + S;
    double base = (double)(V - K) * e_tinyD / Z1;
    double thresh = 1.0 - (double)topp[r];
    unsigned flag = (t >= 1 && t < K && (base + suf_t / Z1) <= thresh) ? 1u : 0u;
    unsigned fr = wave_sum_u(flag);
    if (lane == 0) wU[wid] = fr;
    __syncthreads();
    int cm = (int)(wU[0] + wU[1] + wU[2] + wU[3]);
    int ns = K - cm;              // >= 1 (reference forces top element kept)
    __syncthreads();
    double e2 = (t < ns) ? e_t : 0.0;
    double r2 = wave_sum_d(e2);
    if (lane == 0) wD[wid] = r2;
    __syncthreads();
    double S2 = wD[0] + wD[1] + wD[2] + wD[3];
    float tiny_e = expf(FP16_TINY - Mxf);
    double Z2 = (double)(V - ns) * (double)tiny_e + S2;
    float invZ2 = (float)(1.0 / Z2);
    if (t == 0) {
        params[r] = make_float4(key_inv((unsigned)(kv[ns - 1] >> 32)), Mxf,
                                invZ2, tiny_e * invZ2);
        kn[r] = (unsigned)ns;
    }
    // keep-list: kept set == kv[0..ns)
    if (t < ns) {
        unsigned long long e = kv[t];
        unsigned key = (unsigned)(e >> 32);
        kidx[(size_t)r * 256 + t] = (int)(e & 0xFFFFFFFFu);
        kprob[(size_t)r * 256 + t] = expf(key_inv(key) - Mxf) * invZ2;
    }
}

// Final pass: pure ptiny fill + <=256 scattered keep overwrites per row.
__global__ __launch_bounds__(256) void k_final(
    const float4* __restrict__ params, const unsigned* __restrict__ kn,
    const int* __restrict__ kidx, const float* __restrict__ kprob,
    float* __restrict__ probs)
{
    int r = blockIdx.y;
    int c0 = blockIdx.x * SLICE;
    int t = threadIdx.x;
    float ptiny = params[r].w;
    float* orow = probs + (size_t)r * V;
    float4 pv4 = make_float4(ptiny, ptiny, ptiny, ptiny);
#pragma unroll
    for (int it = 0; it < ITERS; it++) {
        int i = c0 + it * 1024 + t * 4;
        *(float4*)(orow + i) = pv4;
    }
    __syncthreads();
    int ns = (int)kn[r];
    int hi = c0 + SLICE;
    for (int i = t; i < ns; i += 256) {
        int idx = kidx[(size_t)r * 256 + i];
        if (idx >= c0 && idx < hi) orow[idx] = kprob[(size_t)r * 256 + i];
    }
}

extern "C" void kernel_launch(void* const* d_in, const int* in_sizes, int n_in,
                              void* d_out, int out_size, void* d_ws, size_t ws_size,
                              hipStream_t stream) {
    const float* logits = (const float*)d_in[0];
    const int* ptok     = (const int*)d_in[1];
    const int* otok     = (const int*)d_in[2];
    const float* pres   = (const float*)d_in[3];
    // d_in[4] = frequency_penalties: computed but never applied in reference
    const float* rep    = (const float*)d_in[5];
    const float* temp   = (const float*)d_in[6];
    const int* topk     = (const int*)d_in[7];
    const float* topp   = (const float*)d_in[8];

    float* out_probs = (float*)d_out;
    float* out_pm = out_probs + (size_t)B * V;
    float* out_om = out_pm + (size_t)B * V;

    unsigned* ws0 = (unsigned*)d_ws;
    float4* params = (float4*)d_ws;              // 128 * 16B at ws base
    unsigned* cnt  = ws0 + 512;                  // 128 u32
    unsigned* kn   = ws0 + 640;                  // 128 u32
    unsigned long long* cand =
        (unsigned long long*)(ws0 + 768);        // 8B-aligned; 128*CAP u64
    int* kidx      = (int*)(cand + (size_t)B * CAP);   // 128*256 i32
    float* kprob   = (float*)(kidx + B * 256);         // 128*256 f32

    // zero per-row candidate counters (tiny; graph-capture-safe)
    hipMemsetAsync(cnt, 0, B * sizeof(unsigned), stream);

    dim3 g(BPR, B);
    k_main<<<g, 256, 0, stream>>>(logits, ptok, otok, rep, pres, temp,
                                  out_pm, out_om, cnt, cand);
    k_select<<<B, 256, 0, stream>>>(cnt, cand, topk, topp,
                                    params, kn, kidx, kprob);
    k_final<<<g, 256, 0, stream>>>(params, kn, kidx, kprob, out_probs);
}